// Round 12
// baseline (138.758 us; speedup 1.0000x reference)
//
#include <hip/hip_runtime.h>
#include <hip/hip_bf16.h>

typedef __attribute__((ext_vector_type(8))) short short8;
typedef __attribute__((ext_vector_type(4))) float f32x4;

#define NTOK   100000
#define H      150
#define NKS    20          // K-steps of 32 (4 segs x 5)
#define BM     64          // token rows per block
#define SLAB   38400       // BM*H*4 bytes per fp32 slab
#define NCHUNK 38          // ceil(SLAB/1024) 1KB DMA chunks
#define BUFB   (NCHUNK*1024)  // 38912 B per LDS buffer (incl. pad)
#define OUTOFF (NTOK * H)
#define XLIM   ((long)NTOK * H * 4 - 16)   // last valid 16B-aligned src offset

__device__ __forceinline__ unsigned short f2bf(float f) {
    unsigned int u = __builtin_bit_cast(unsigned int, f);
    u = (u + 0x7FFFu + ((u >> 16) & 1u)) >> 16;   // RNE
    return (unsigned short)u;
}

// ---------------------------------------------------------------------------
// Prepass: pack weights FRAGMENT-MAJOR so every B-frag load in the main
// kernel is 64 lanes x 16B = 1KB fully contiguous.
// wb[(((n*NKS + ks)*64 + lane)*8 + j] = W_seg[k2][col]
//   seg = ks/5, s5 = ks%5, col = n*16 + (lane&15), k2 = s5*32 + (lane>>4)*8 + j
// ---------------------------------------------------------------------------
__global__ void prep_w(const float* __restrict__ w_in, const float* __restrict__ w_out,
                       const float* __restrict__ u_in, const float* __restrict__ u_out,
                       unsigned short* __restrict__ wb) {
    int idx = blockIdx.x * 256 + threadIdx.x;
    if (idx >= 10 * NKS * 64 * 8) return;        // 102400 elems
    int j    = idx & 7;
    int lane = (idx >> 3) & 63;
    int ks   = (idx >> 9) % NKS;
    int n    = idx / (512 * NKS);
    int seg  = ks / 5, s5 = ks % 5;
    int col  = n * 16 + (lane & 15);
    int k2   = s5 * 32 + (lane >> 4) * 8 + j;
    float v = 0.0f;
    if (col < H && k2 < H) {
        const float* W = (seg == 0) ? w_in : (seg == 1) ? w_out : (seg == 2) ? u_in : u_out;
        v = W[k2 * H + col];
    }
    wb[idx] = f2bf(v);
}

// ---------------------------------------------------------------------------
// Main fused kernel. Block = 64 token rows x 160 cols; 4 waves in 2M x 2N:
// each wave 32 rows x 80 cols (acc[2][5]). Halves redundant B L2 traffic vs
// the 16-rows-x-all-cols mapping (5 B-frag loads/K-step instead of 10).
// X staged fp32 via global_load_lds width=16 (zero-VGPR DMA, linear dest);
// double-buffered; per segment {stage(seg+1) -> 5 K-steps -> barrier}.
// ---------------------------------------------------------------------------
__global__ __launch_bounds__(256, 2) void lstm_fused(
        const float* __restrict__ s_in, const float* __restrict__ s_out,
        const float* __restrict__ h_in, const float* __restrict__ h_out,
        const float* __restrict__ last_c, const unsigned short* __restrict__ wb,
        float* __restrict__ out) {
    __shared__ __align__(16) unsigned char Xr[2][BUFB];   // 77824 B -> 2 blocks/CU

    const int t     = threadIdx.x;
    const int lane  = t & 63;
    const int wid   = t >> 6;      // 0..3
    const int waveM = wid >> 1;    // 0..1 -> rows waveM*32 + [0,32)
    const int waveN = wid & 1;     // 0..1 -> cols waveN*80 + [0,80)
    const int lrow  = lane & 15;   // A row in frag / B+C col in frag
    const int lko   = lane >> 4;   // k-group 0..3 / C row-group
    const int r0blk = blockIdx.x * BM;

    const float* Xseg[4] = {s_in, s_out, h_in, h_out};

    f32x4 acc[2][5];
#pragma unroll
    for (int m = 0; m < 2; m++)
#pragma unroll
        for (int n = 0; n < 5; n++) acc[m][n] = (f32x4){0.f, 0.f, 0.f, 0.f};

    // ---- DMA stage: wave-striped 1KB chunks, zero VGPR cost ----
    auto stage = [&](int seg, int buf) {
        const char* base = (const char*)Xseg[seg];
        const long sofs = (long)r0blk * (H * 4);
        for (int c = wid; c < NCHUNK; c += 4) {
            long go = sofs + c * 1024 + lane * 16;
            if (go > XLIM) go = XLIM;              // tail-block clamp (valid floats)
            const void* gp = base + go;
            void* lp = &Xr[buf][c * 1024];         // wave-uniform dest
            __builtin_amdgcn_global_load_lds(
                (const __attribute__((address_space(1))) void*)gp,
                (__attribute__((address_space(3))) void*)lp, 16, 0, 0);
        }
    };

    stage(0, 0);
    __syncthreads();   // drains stage-0 DMA (vmcnt) + sync

    for (int seg = 0; seg < 4; seg++) {
        if (seg < 3) stage(seg + 1, (seg + 1) & 1);   // in flight under compute

        const float* Xf = (const float*)&Xr[seg & 1][0];   // [64][150] fp32

        // ---- compute: 5 K-steps of {5 B-loads + 2 A-frags + 10 MFMA} ----
#pragma unroll
        for (int s5 = 0; s5 < 5; s5++) {
            const int ks = seg * 5 + s5;
            short8 bf[5];
#pragma unroll
            for (int n = 0; n < 5; n++)
                bf[n] = *(const short8*)&wb[((((long)waveN * 5 + n) * NKS + ks) * 64 + lane) * 8];

            const int k0 = s5 * 32 + lko * 8;
            short8 af[2];
#pragma unroll
            for (int m = 0; m < 2; m++) {
                const int row = waveM * 32 + m * 16 + lrow;
                const float* rp = Xf + row * H + k0;   // 8B-aligned
                float xv[8];
#pragma unroll
                for (int j = 0; j < 8; j += 2) {
                    float2 v = *(const float2*)&rp[j];
                    xv[j] = v.x; xv[j + 1] = v.y;
                }
                if (s5 == 4) {                          // k0 = 128+lko*8; mask k >= 150
#pragma unroll
                    for (int j = 0; j < 8; j++)
                        xv[j] = (k0 + j < H) ? xv[j] : 0.f;
                }
#pragma unroll
                for (int j = 0; j < 8; j++) af[m][j] = (short)f2bf(xv[j]);
            }

#pragma unroll
            for (int m = 0; m < 2; m++)
#pragma unroll
                for (int n = 0; n < 5; n++)
                    acc[m][n] = __builtin_amdgcn_mfma_f32_16x16x32_bf16(af[m], bf[n], acc[m][n], 0, 0, 0);
        }
        __syncthreads();   // next tile's DMA done; buffer reuse safe
    }

    // ---- fused epilogue: g=sigmoid(pre); cell=g*lc+g*g; hid=g*tanh(cell)
#pragma unroll
    for (int m = 0; m < 2; m++) {
#pragma unroll
        for (int r = 0; r < 4; r++) {
            const int row = r0blk + waveM * 32 + m * 16 + lko * 4 + r;
            if (row >= NTOK) continue;
            const long rb = (long)row * H;
#pragma unroll
            for (int n = 0; n < 5; n++) {
                const int col = waveN * 80 + n * 16 + lrow;
                if (col >= H) continue;
                float pre = acc[m][n][r];
                float e   = __expf(-pre);
                float g   = __builtin_amdgcn_rcpf(1.f + e);
                float lc  = last_c[rb + col];
                float cell = g * lc + g * g;
                float e2  = __expf(-2.f * cell);
                float th  = (1.f - e2) * __builtin_amdgcn_rcpf(1.f + e2);
                out[rb + col]          = g * th;
                out[OUTOFF + rb + col] = cell;
            }
        }
    }
}

extern "C" void kernel_launch(void* const* d_in, const int* in_sizes, int n_in,
                              void* d_out, int out_size, void* d_ws, size_t ws_size,
                              hipStream_t stream) {
    const float* s_in   = (const float*)d_in[0];
    const float* s_out  = (const float*)d_in[1];
    const float* h_in   = (const float*)d_in[2];
    const float* h_out  = (const float*)d_in[3];
    const float* last_c = (const float*)d_in[4];
    const float* w_in   = (const float*)d_in[5];
    const float* w_out  = (const float*)d_in[6];
    const float* u_in   = (const float*)d_in[7];
    const float* u_out  = (const float*)d_in[8];

    unsigned short* wb = (unsigned short*)d_ws;   // 102400*2 = 204800 B
    float* out = (float*)d_out;

    prep_w<<<(10 * NKS * 64 * 8 + 255) / 256, 256, 0, stream>>>(w_in, w_out, u_in, u_out, wb);

    const int nblocks = (NTOK + BM - 1) / BM;  // 1563 blocks, 4 waves (2Mx2N)
    lstm_fused<<<nblocks, 256, 0, stream>>>(s_in, s_out, h_in, h_out, last_c, wb, out);
}

// Round 13
// 128.278 us; speedup vs baseline: 1.0817x; 1.0817x over previous
//
#include <hip/hip_runtime.h>
#include <hip/hip_bf16.h>

typedef __attribute__((ext_vector_type(8))) short short8;
typedef __attribute__((ext_vector_type(4))) float f32x4;

#define NTOK   100000
#define H      150
#define NKS    20          // K-steps of 32 (4 segs x 5)
#define BM     64          // token rows per block
#define NCHUNK 38          // ceil(BM*H*4 / 1024) 1KB DMA chunks
#define BUFB   (NCHUNK*1024)  // 38912 B per LDS buffer
#define OUTOFF (NTOK * H)
#define XLIM   ((long)NTOK * H * 4 - 16)   // last valid 16B-aligned src offset

__device__ __forceinline__ unsigned short f2bf(float f) {
    unsigned int u = __builtin_bit_cast(unsigned int, f);
    u = (u + 0x7FFFu + ((u >> 16) & 1u)) >> 16;   // RNE
    return (unsigned short)u;
}

// ---------------------------------------------------------------------------
// Prepass: pack weights FRAGMENT-MAJOR so every B-frag load in the main
// kernel is 64 lanes x 16B = 1KB fully contiguous.
// wb[(((n*NKS + ks)*64 + lane)*8 + j] = W_seg[k2][col]
//   seg = ks/5, s5 = ks%5, col = n*16 + (lane&15), k2 = s5*32 + (lane>>4)*8 + j
// ---------------------------------------------------------------------------
__global__ void prep_w(const float* __restrict__ w_in, const float* __restrict__ w_out,
                       const float* __restrict__ u_in, const float* __restrict__ u_out,
                       unsigned short* __restrict__ wb) {
    int idx = blockIdx.x * 256 + threadIdx.x;
    if (idx >= 10 * NKS * 64 * 8) return;        // 102400 elems
    int j    = idx & 7;
    int lane = (idx >> 3) & 63;
    int ks   = (idx >> 9) % NKS;
    int n    = idx / (512 * NKS);
    int seg  = ks / 5, s5 = ks % 5;
    int col  = n * 16 + (lane & 15);
    int k2   = s5 * 32 + (lane >> 4) * 8 + j;
    float v = 0.0f;
    if (col < H && k2 < H) {
        const float* W = (seg == 0) ? w_in : (seg == 1) ? w_out : (seg == 2) ? u_in : u_out;
        v = W[k2 * H + col];
    }
    wb[idx] = f2bf(v);
}

// ---------------------------------------------------------------------------
// Main fused kernel. Block = 64 rows x 160 cols; 4 waves in 2M x 2N (each
// wave 32 rows x 80 cols, acc[2][5]).
// KEY CHANGE vs r12: per segment, ALL 25 B-fragments are batch-loaded into
// VGPRs BEFORE the next-segment DMA is issued (order pinned by
// sched_barrier). vmcnt is a FIFO: with [25 B][10 DMA] issue order, the
// K-loop's B-waits never require the DMA to complete, so the DMA truly
// overlaps the compute phase and drains only at the segment barrier.
// Stage is statically 10 chunks/wave so the compiler can count vmcnt.
// ---------------------------------------------------------------------------
__global__ __launch_bounds__(256, 2) void lstm_fused(
        const float* __restrict__ s_in, const float* __restrict__ s_out,
        const float* __restrict__ h_in, const float* __restrict__ h_out,
        const float* __restrict__ last_c, const unsigned short* __restrict__ wb,
        float* __restrict__ out) {
    __shared__ __align__(16) unsigned char Xr[2][BUFB];   // 77824 B -> 2 blocks/CU

    const int t     = threadIdx.x;
    const int lane  = t & 63;
    const int wid   = t >> 6;      // 0..3
    const int waveM = wid >> 1;    // rows waveM*32 + [0,32)
    const int waveN = wid & 1;     // cols waveN*80 + [0,80)
    const int lrow  = lane & 15;   // A row in frag / B+C col in frag
    const int lko   = lane >> 4;   // k-group 0..3 / C row-group
    const int r0blk = blockIdx.x * BM;

    const float* Xseg[4] = {s_in, s_out, h_in, h_out};

    f32x4 acc[2][5];
#pragma unroll
    for (int m = 0; m < 2; m++)
#pragma unroll
        for (int n = 0; n < 5; n++) acc[m][n] = (f32x4){0.f, 0.f, 0.f, 0.f};

    // ---- DMA stage: statically 10 chunks per wave (waves 2,3 re-write
    //      chunks 0,1 with identical data -> benign; keeps vmcnt countable)
    auto stage = [&](int seg, int buf) {
        const char* base = (const char*)Xseg[seg];
        const long sofs = (long)r0blk * (H * 4);
#pragma unroll
        for (int i = 0; i < 10; i++) {
            int c = wid + i * 4;
            int cc = (c < NCHUNK) ? c : (c - NCHUNK);   // wave-uniform
            long go = sofs + cc * 1024 + lane * 16;
            if (go > XLIM) go = XLIM;                   // tail-block clamp
            const void* gp = base + go;
            void* lp = &Xr[buf][cc * 1024];             // wave-uniform dest
            __builtin_amdgcn_global_load_lds(
                (const __attribute__((address_space(1))) void*)gp,
                (__attribute__((address_space(3))) void*)lp, 16, 0, 0);
        }
    };

    stage(0, 0);
    __syncthreads();   // drains stage-0 DMA + sync

    for (int seg = 0; seg < 4; seg++) {
        // ---- 1) batch ALL 25 B-frag loads for this segment (L2-resident) ----
        short8 bseg[5][5];
#pragma unroll
        for (int s5 = 0; s5 < 5; s5++)
#pragma unroll
            for (int n = 0; n < 5; n++)
                bseg[s5][n] = *(const short8*)
                    &wb[((((long)waveN * 5 + n) * NKS + seg * 5 + s5) * 64 + lane) * 8];

        __builtin_amdgcn_sched_barrier(0);   // pin: B batch issued before DMA

        // ---- 2) issue next-segment DMA (sits at the BACK of the vmcnt FIFO) ----
        if (seg < 3) stage(seg + 1, (seg + 1) & 1);

        __builtin_amdgcn_sched_barrier(0);   // pin: DMA issued before compute

        // ---- 3) compute: 5 K-steps on registers + LDS only ----
        const float* Xf = (const float*)&Xr[seg & 1][0];   // [64][150] fp32
#pragma unroll
        for (int s5 = 0; s5 < 5; s5++) {
            const int k0 = s5 * 32 + lko * 8;
            short8 af[2];
#pragma unroll
            for (int m = 0; m < 2; m++) {
                const int row = waveM * 32 + m * 16 + lrow;
                const float* rp = Xf + row * H + k0;   // 8B-aligned
                float xv[8];
#pragma unroll
                for (int j = 0; j < 8; j += 2) {
                    float2 v = *(const float2*)&rp[j];
                    xv[j] = v.x; xv[j + 1] = v.y;
                }
                if (s5 == 4) {                          // mask k >= 150
#pragma unroll
                    for (int j = 0; j < 8; j++)
                        xv[j] = (k0 + j < H) ? xv[j] : 0.f;
                }
#pragma unroll
                for (int j = 0; j < 8; j++) af[m][j] = (short)f2bf(xv[j]);
            }
#pragma unroll
            for (int m = 0; m < 2; m++)
#pragma unroll
                for (int n = 0; n < 5; n++)
                    acc[m][n] = __builtin_amdgcn_mfma_f32_16x16x32_bf16(af[m], bseg[s5][n], acc[m][n], 0, 0, 0);
        }
        __syncthreads();   // next tile's DMA done; buffer reuse safe
    }

    // ---- fused epilogue: g=sigmoid(pre); cell=g*lc+g*g; hid=g*tanh(cell)
#pragma unroll
    for (int m = 0; m < 2; m++) {
#pragma unroll
        for (int r = 0; r < 4; r++) {
            const int row = r0blk + waveM * 32 + m * 16 + lko * 4 + r;
            if (row >= NTOK) continue;
            const long rb = (long)row * H;
#pragma unroll
            for (int n = 0; n < 5; n++) {
                const int col = waveN * 80 + n * 16 + lrow;
                if (col >= H) continue;
                float pre = acc[m][n][r];
                float e   = __expf(-pre);
                float g   = __builtin_amdgcn_rcpf(1.f + e);
                float lc  = last_c[rb + col];
                float cell = g * lc + g * g;
                float e2  = __expf(-2.f * cell);
                float th  = (1.f - e2) * __builtin_amdgcn_rcpf(1.f + e2);
                out[rb + col]          = g * th;
                out[OUTOFF + rb + col] = cell;
            }
        }
    }
}

extern "C" void kernel_launch(void* const* d_in, const int* in_sizes, int n_in,
                              void* d_out, int out_size, void* d_ws, size_t ws_size,
                              hipStream_t stream) {
    const float* s_in   = (const float*)d_in[0];
    const float* s_out  = (const float*)d_in[1];
    const float* h_in   = (const float*)d_in[2];
    const float* h_out  = (const float*)d_in[3];
    const float* last_c = (const float*)d_in[4];
    const float* w_in   = (const float*)d_in[5];
    const float* w_out  = (const float*)d_in[6];
    const float* u_in   = (const float*)d_in[7];
    const float* u_out  = (const float*)d_in[8];

    unsigned short* wb = (unsigned short*)d_ws;   // 102400*2 = 204800 B
    float* out = (float*)d_out;

    prep_w<<<(10 * NKS * 64 * 8 + 255) / 256, 256, 0, stream>>>(w_in, w_out, u_in, u_out, wb);

    const int nblocks = (NTOK + BM - 1) / BM;  // 1563 blocks, 4 waves (2Mx2N)
    lstm_fused<<<nblocks, 256, 0, stream>>>(s_in, s_out, h_in, h_out, last_c, wb, out);
}